// Round 1
// 860.932 us; speedup vs baseline: 1.2759x; 1.2759x over previous
//
#include <hip/hip_runtime.h>
#include <math.h>

typedef unsigned short u16;
typedef unsigned int u32;
typedef __attribute__((ext_vector_type(2))) _Float16 h2;

#define kT 32
#define OUT_STATES 1048576   // T*B*D
#define OUT_M      1179648   // + 4*B*D

union H2U { u32 u; h2 h; };

__device__ __forceinline__ float dot2u(u32 w, u32 x, float acc){
  H2U a; a.u = w; H2U b; b.u = x;
#if __has_builtin(__builtin_amdgcn_fdot2)
  return __builtin_amdgcn_fdot2(a.h, b.h, acc, false);
#else
  acc += (float)a.h.x * (float)b.h.x;
  acc += (float)a.h.y * (float)b.h.y;
  return acc;
#endif
}

__device__ __forceinline__ u32 packf16(float x, float y){
  H2U v; v.h.x = (_Float16)x; v.h.y = (_Float16)y; return v.u;
}

// ---- prep: weights -> packed f16 [k/2][col] layout, biases summed, mask ------
// idx map: WAp [0,262144) | WEp [262144,524288) | Wcp [524288,589824) |
//          bA [589824,590848) | bE [590848,591872) | bc [591872,592128) |
//          mask [592128,723200) | prog-zero [723200,723328)
__global__ __launch_bounds__(1024) void k_prep(
        const float* __restrict__ Wih_r, const float* __restrict__ Whh_r,
        const float* __restrict__ bih_r, const float* __restrict__ bhh_r,
        const float* __restrict__ Wc,    const float* __restrict__ bc,
        const float* __restrict__ Wih_w, const float* __restrict__ Whh_w,
        const float* __restrict__ bih_w, const float* __restrict__ bhh_w,
        const unsigned char* __restrict__ maskraw,
        u32* WAp, u32* WEp, u32* Wcp, float* bA, float* bE, float* bcf,
        unsigned char* mbuf, u32* prog){
  int idx = blockIdx.x * 1024 + threadIdx.x;
  if (idx < 262144){
    int kp = idx >> 10, col = idx & 1023;
    int k0 = 2 * kp;
    float v0 = (k0 < 256) ? Wih_r[col * 256 + k0] : Whh_r[col * 256 + k0 - 256];
    float v1 = (k0 + 1 < 256) ? Wih_r[col * 256 + k0 + 1]
                              : Whh_r[col * 256 + k0 + 1 - 256];
    WAp[idx] = packf16(v0, v1);
  } else if (idx < 524288){
    int i = idx - 262144;
    int kp = i >> 10, col = i & 1023;
    int k0 = 2 * kp;
    float v0 = (k0 < 256) ? Wih_w[col * 256 + k0] : Whh_w[col * 256 + k0 - 256];
    float v1 = (k0 + 1 < 256) ? Wih_w[col * 256 + k0 + 1]
                              : Whh_w[col * 256 + k0 + 1 - 256];
    WEp[i] = packf16(v0, v1);
  } else if (idx < 589824){
    int i = idx - 524288;
    int kp = i >> 8, col = i & 255;
    int k0 = 2 * kp;
    Wcp[i] = packf16(Wc[col * 512 + k0], Wc[col * 512 + k0 + 1]);
  } else if (idx < 590848){
    int i = idx - 589824;
    bA[i] = bih_r[i] + bhh_r[i];
  } else if (idx < 591872){
    int i = idx - 590848;
    bE[i] = bih_w[i] + bhh_w[i];
  } else if (idx < 592128){
    int i = idx - 591872;
    bcf[i] = bc[i];
  } else if (idx < 723200){
    int l = idx - 592128;
    // Detect mask storage: int32 / u8(bool) / bf16 / fp32 from first 512 bytes.
    bool sawBig = false, sawOdd = false, saw3F1 = false;
    for (int i = 0; i < 512; i++){
      unsigned char c = maskraw[i];
      if (c > 1u) sawBig = true;
      if ((i & 3) != 0 && c != 0) sawOdd = true;
      if ((i & 3) == 1 && c == 0x3F) saw3F1 = true;
    }
    int mode = (!sawBig) ? (sawOdd ? 1 : 0) : (saw3F1 ? 2 : 3);
    unsigned char mv;
    if      (mode == 0) mv = (((const int*)maskraw)[l] != 0);
    else if (mode == 1) mv = (maskraw[l] != 0);
    else if (mode == 2) mv = ((maskraw[2*l] | maskraw[2*l+1]) != 0);
    else                mv = (((const unsigned int*)maskraw)[l] != 0);
    mbuf[l] = mv;
  } else if (idx < 723328){
    prog[idx - 723200] = 0;     // reset producer progress counters each launch
  }
}

// gemv: 1024 cols, K=512 (256 half2 rows). thread = (cg 4 cols, ks of 4 slices)
// Coalesced: lanes -> consecutive cg -> consecutive 16B. x broadcast from LDS.
__device__ __forceinline__ void gemv1024(const u32* __restrict__ W,
        const u32* xh, float* psum, int tid){
  int cg = tid & 255, ks = tid >> 8;
  const uint4* wp = (const uint4*)W + (size_t)ks * 64 * 256 + cg;
  const u32* xk = xh + ks * 64;
  float a0 = 0.f, a1 = 0.f, a2 = 0.f, a3 = 0.f;
  #pragma unroll 8
  for (int i = 0; i < 64; i++){
    uint4 wv = wp[(size_t)i * 256];
    u32 xp = xk[i];
    a0 = dot2u(wv.x, xp, a0);  a1 = dot2u(wv.y, xp, a1);
    a2 = dot2u(wv.z, xp, a2);  a3 = dot2u(wv.w, xp, a3);
  }
  float4 r; r.x = a0; r.y = a1; r.z = a2; r.w = a3;
  *(float4*)&psum[ks * 1024 + cg * 4] = r;
}

// ---- main: 256 blocks. blocks [0,128) = read-LSTM producer for row b,
//            blocks [128,256) = attention/comp/write-LSTM consumer for row b.
// Producer->consumer handoff of hr_t via agent-scope relaxed atomics (coherence
// point), ordered by __syncthreads()'s vmcnt(0) drain before the flag store.
// All 256 blocks are guaranteed co-resident (16 waves, ~29KB LDS -> >=1/CU).
__global__ __launch_bounds__(1024, 4) void k_main(
        const float* __restrict__ emb, const float* __restrict__ hr0,
        const float* __restrict__ cr0, const float* __restrict__ hw0,
        const float* __restrict__ cw0, const float* __restrict__ M0,
        const u32* __restrict__ WAp, const u32* __restrict__ WEp,
        const u32* __restrict__ Wcp, const float* __restrict__ bA,
        const float* __restrict__ bE, const float* __restrict__ bcf,
        const unsigned char* __restrict__ mbuf,
        float* __restrict__ hrbuf, u32* __restrict__ prog,
        float* __restrict__ out){
  __shared__ u32 xh[256];                                   // packed f16 x
  __shared__ __attribute__((aligned(16))) float hr_s[256];
  __shared__ __attribute__((aligned(16))) float hw_f[256];
  __shared__ float m_f[256], comp_f[256], cr_l[256], cw_l[256];
  __shared__ __attribute__((aligned(16))) float psum[4160];
  __shared__ float z_lds[1024];
  __shared__ float redA[16], redB[16], redC[16], redD[16], wred[16], sred[16];
  __shared__ unsigned char mk[1024];

  int bid = blockIdx.x;
  int role = bid >> 7, b = bid & 127;
  int tid = threadIdx.x;
  int w = tid >> 6, lane = tid & 63;

  if (role == 0){
    // ================= R: read-LSTM chain (producer) =================
    if (tid < 256){
      hr_s[tid] = hr0[b * 256 + tid];
      cr_l[tid] = cr0[b * 256 + tid];
    }
    float2 e2 = make_float2(0.f, 0.f);
    if (tid < 128) e2 = *(const float2*)(emb + b * 256 + 2 * tid);
    __syncthreads();

    for (int t = 0; t < kT; t++){
      if (tid < 128) xh[tid] = packf16(e2.x, e2.y);
      else if (tid < 256){
        int j = tid - 128;
        xh[tid] = packf16(hr_s[2 * j], hr_s[2 * j + 1]);
      }
      __syncthreads();
      if (tid < 128 && t + 1 < kT)   // prefetch next emb row under the gemv
        e2 = *(const float2*)(emb + (size_t)(t + 1) * 32768 + b * 256 + 2 * tid);
      gemv1024(WAp, xh, psum, tid);
      __syncthreads();
      if (tid < 256){
        float gi = bA[tid], gf = bA[256 + tid];
        float gg = bA[512 + tid], go = bA[768 + tid];
        #pragma unroll
        for (int ks = 0; ks < 4; ks++){
          gi += psum[ks * 1024 + tid];
          gf += psum[ks * 1024 + 256 + tid];
          gg += psum[ks * 1024 + 512 + tid];
          go += psum[ks * 1024 + 768 + tid];
        }
        float i_ = 1.f / (1.f + expf(-gi));
        float f_ = 1.f / (1.f + expf(-gf));
        float g_ = tanhf(gg);
        float o_ = 1.f / (1.f + expf(-go));
        float c2 = f_ * cr_l[tid] + i_ * g_;
        cr_l[tid] = c2;
        float h = o_ * tanhf(c2);
        hr_s[tid] = h;
        __hip_atomic_store(hrbuf + (size_t)t * 32768 + b * 256 + tid, h,
                           __ATOMIC_RELAXED, __HIP_MEMORY_SCOPE_AGENT);
      }
      __syncthreads();  // vmcnt(0) drain: hr atomics complete before flag
      if (tid == 0)
        __hip_atomic_store(prog + b, (u32)(t + 1),
                           __ATOMIC_RELAXED, __HIP_MEMORY_SCOPE_AGENT);
    }
    if (tid < 256){
      out[OUT_STATES          + b * 256 + tid] = hr_s[tid];
      out[OUT_STATES +  32768 + b * 256 + tid] = cr_l[tid];
    }
    return;
  }

  // ================= W: attention + comp + write-LSTM (consumer) ============
  if (tid < 256){
    hw_f[tid] = hw0[b * 256 + tid];
    cw_l[tid] = cw0[b * 256 + tid];
  }
  unsigned char mreg = mbuf[b * 1024 + tid];
  mk[tid] = mreg;
  float zreg = 0.f;
  __syncthreads();

  for (int t = 0; t < kT; t++){
    // ---------- wait for hr_t from the producer ----------
    if (tid == 0){
      while (__hip_atomic_load(prog + b, __ATOMIC_RELAXED,
                               __HIP_MEMORY_SCOPE_AGENT) < (u32)(t + 1))
        __builtin_amdgcn_s_sleep(2);
    }
    __syncthreads();
    if (tid < 256)
      hr_s[tid] = __hip_atomic_load(hrbuf + (size_t)t * 32768 + b * 256 + tid,
                                    __ATOMIC_RELAXED, __HIP_MEMORY_SCOPE_AGENT);
    __syncthreads();

    // ---------- Phase C: attention ----------
    if (t == 0){
      // per-wave flash scan over 64 rows of M0[b]
      float4 hrv = *(const float4*)&hr_s[lane * 4];
      float run_max = -INFINITY, S = 0.f;
      float m0 = 0.f, m1 = 0.f, m2 = 0.f, m3 = 0.f;
      for (int l = w * 64; l < w * 64 + 64; ++l){
        float4 Mv = *(const float4*)(M0 + ((size_t)b * 1024 + l) * 256 + lane * 4);
        float part = Mv.x * hrv.x + Mv.y * hrv.y + Mv.z * hrv.z + Mv.w * hrv.w;
        #pragma unroll
        for (int mm = 32; mm >= 1; mm >>= 1) part += __shfl_xor(part, mm, 64);
        float s = mk[l] ? -INFINITY : part;
        if (lane == 0) z_lds[l] = s;
        float nm = fmaxf(run_max, s);
        if (nm > -INFINITY){
          float sc = expf(run_max - nm);
          float p  = expf(s - nm);
          S = S * sc + p;
          m0 = m0 * sc + p * Mv.x;  m1 = m1 * sc + p * Mv.y;
          m2 = m2 * sc + p * Mv.z;  m3 = m3 * sc + p * Mv.w;
          run_max = nm;
        }
      }
      if (lane == 0){ wred[w] = run_max; sred[w] = S; }
      psum[w * 260 + lane * 4 + 0] = m0;
      psum[w * 260 + lane * 4 + 1] = m1;
      psum[w * 260 + lane * 4 + 2] = m2;
      psum[w * 260 + lane * 4 + 3] = m3;
      __syncthreads();
      float gmax = -INFINITY;
      #pragma unroll
      for (int w2 = 0; w2 < 16; w2++) gmax = fmaxf(gmax, wred[w2]);
      float Sg = 0.f;
      #pragma unroll
      for (int w2 = 0; w2 < 16; w2++) Sg += sred[w2] * expf(wred[w2] - gmax);
      zreg = expf(z_lds[tid] - gmax) / Sg;
      if (tid < 256){
        float mv = 0.f;
        #pragma unroll
        for (int w2 = 0; w2 < 16; w2++)
          mv += psum[w2 * 260 + tid] * expf(wred[w2] - gmax);
        m_f[tid] = mv / Sg;
      }
    } else {
      // factored memory: M = (1-zp) + hw_prev (x) zp
      float hrv = (tid < 256) ? hr_s[tid] : 0.f;
      float hwv = (tid < 256) ? hw_f[tid] : 0.f;
      float v1 = hrv, v2 = hrv * hwv;
      #pragma unroll
      for (int mm = 32; mm >= 1; mm >>= 1){
        v1 += __shfl_xor(v1, mm, 64);  v2 += __shfl_xor(v2, mm, 64);
      }
      if (lane == 0){ redA[w] = v1; redB[w] = v2; }
      __syncthreads();
      float S1 = 0.f, S2 = 0.f;
      #pragma unroll
      for (int i = 0; i < 16; i++){ S1 += redA[i]; S2 += redB[i]; }
      float zold = zreg;
      float s = mreg ? -INFINITY : (1.f - zold) * S1 + zold * S2;
      float mx = s;
      #pragma unroll
      for (int mm = 32; mm >= 1; mm >>= 1) mx = fmaxf(mx, __shfl_xor(mx, mm, 64));
      if (lane == 0) redC[w] = mx;
      __syncthreads();
      float gmax = -INFINITY;
      #pragma unroll
      for (int i = 0; i < 16; i++) gmax = fmaxf(gmax, redC[i]);
      float p = expf(s - gmax);            // -inf -> 0
      float ps = p;
      #pragma unroll
      for (int mm = 32; mm >= 1; mm >>= 1) ps += __shfl_xor(ps, mm, 64);
      if (lane == 0) redD[w] = ps;
      __syncthreads();
      float Ssum = 0.f;
      #pragma unroll
      for (int i = 0; i < 16; i++) Ssum += redD[i];
      float znew = p / Ssum;
      float a1 = znew * (1.f - zold), a2 = znew * zold;
      #pragma unroll
      for (int mm = 32; mm >= 1; mm >>= 1){
        a1 += __shfl_xor(a1, mm, 64);  a2 += __shfl_xor(a2, mm, 64);
      }
      if (lane == 0){ redA[w] = a1; redB[w] = a2; }
      __syncthreads();
      float Ab = 0.f, Cb = 0.f;
      #pragma unroll
      for (int i = 0; i < 16; i++){ Ab += redA[i]; Cb += redB[i]; }
      zreg = znew;
      if (tid < 256) m_f[tid] = Ab + hw_f[tid] * Cb;
    }
    __syncthreads();

    // ---------- comp = softmax(Wc @ [hr;m] + bc) ----------
    if (tid < 128) xh[tid] = packf16(hr_s[2 * tid], hr_s[2 * tid + 1]);
    else if (tid < 256){
      int j = tid - 128;
      xh[tid] = packf16(m_f[2 * j], m_f[2 * j + 1]);
    }
    __syncthreads();
    {
      int cg = tid & 63, ks = tid >> 6;
      const uint4* wp = (const uint4*)Wcp + ks * 16 * 64 + cg;
      const u32* xk = xh + ks * 16;
      float a0 = 0.f, a1 = 0.f, a2 = 0.f, a3 = 0.f;
      #pragma unroll
      for (int i = 0; i < 16; i++){
        uint4 wv = wp[i * 64];
        u32 xp = xk[i];
        a0 = dot2u(wv.x, xp, a0);  a1 = dot2u(wv.y, xp, a1);
        a2 = dot2u(wv.z, xp, a2);  a3 = dot2u(wv.w, xp, a3);
      }
      float4 r; r.x = a0; r.y = a1; r.z = a2; r.w = a3;
      *(float4*)&psum[ks * 256 + cg * 4] = r;
    }
    __syncthreads();
    {
      float e = -INFINITY;
      if (tid < 256){
        e = bcf[tid];
        #pragma unroll
        for (int s2 = 0; s2 < 16; s2++) e += psum[s2 * 256 + tid];
      }
      float mx = e;
      #pragma unroll
      for (int mm = 32; mm >= 1; mm >>= 1) mx = fmaxf(mx, __shfl_xor(mx, mm, 64));
      if (lane == 0) redC[w] = mx;
      __syncthreads();
      float emax = -INFINITY;
      #pragma unroll
      for (int i = 0; i < 16; i++) emax = fmaxf(emax, redC[i]);
      float pe = (tid < 256) ? expf(e - emax) : 0.f;
      float ps = pe;
      #pragma unroll
      for (int mm = 32; mm >= 1; mm >>= 1) ps += __shfl_xor(ps, mm, 64);
      if (lane == 0) redD[w] = ps;
      __syncthreads();
      float esum = 0.f;
      #pragma unroll
      for (int i = 0; i < 16; i++) esum += redD[i];
      if (tid < 256) comp_f[tid] = pe / esum;
    }
    __syncthreads();

    // ---------- Phase E: write-LSTM ----------
    if (tid < 128) xh[tid] = packf16(comp_f[2 * tid], comp_f[2 * tid + 1]);
    else if (tid < 256){
      int j = tid - 128;
      xh[tid] = packf16(hw_f[2 * j], hw_f[2 * j + 1]);
    }
    __syncthreads();
    gemv1024(WEp, xh, psum, tid);
    __syncthreads();
    if (tid < 256){
      float gi = bE[tid], gf = bE[256 + tid];
      float gg = bE[512 + tid], go = bE[768 + tid];
      #pragma unroll
      for (int ks = 0; ks < 4; ks++){
        gi += psum[ks * 1024 + tid];
        gf += psum[ks * 1024 + 256 + tid];
        gg += psum[ks * 1024 + 512 + tid];
        go += psum[ks * 1024 + 768 + tid];
      }
      float i_ = 1.f / (1.f + expf(-gi));
      float f_ = 1.f / (1.f + expf(-gf));
      float g_ = tanhf(gg);
      float o_ = 1.f / (1.f + expf(-go));
      float c2 = f_ * cw_l[tid] + i_ * g_;
      cw_l[tid] = c2;
      float h2v = o_ * tanhf(c2);
      hw_f[tid] = h2v;
      out[(size_t)t * 32768 + b * 256 + tid] = h2v;
    }
    __syncthreads();
  }

  // ---------- epilogue: states + M = (1-z) + hw (x) z ----------
  if (tid < 256){
    out[OUT_STATES +  65536 + b * 256 + tid] = hw_f[tid];
    out[OUT_STATES +  98304 + b * 256 + tid] = cw_l[tid];
  }
  z_lds[tid] = zreg;
  __syncthreads();
  float* Mout = out + OUT_M + (size_t)b * 262144;
  for (int g = tid; g < 65536; g += 1024){
    int l = g >> 6, d0 = (g & 63) << 2;
    float z = z_lds[l], omz = 1.f - z;
    float4 h4 = *(const float4*)&hw_f[d0];
    float4 v;
    v.x = omz + h4.x * z;  v.y = omz + h4.y * z;
    v.z = omz + h4.z * z;  v.w = omz + h4.w * z;
    *(float4*)(Mout + (size_t)l * 256 + d0) = v;
  }
}

extern "C" void kernel_launch(void* const* d_in, const int* in_sizes, int n_in,
                              void* d_out, int out_size, void* d_ws, size_t ws_size,
                              hipStream_t stream){
  const float* emb   = (const float*)d_in[0];
  const float* hr0   = (const float*)d_in[1];
  const float* cr0   = (const float*)d_in[2];
  const float* hw0   = (const float*)d_in[3];
  const float* cw0   = (const float*)d_in[4];
  const float* M0    = (const float*)d_in[5];
  const unsigned char* maskraw = (const unsigned char*)d_in[6];
  const float* Wih_r = (const float*)d_in[7];
  const float* Whh_r = (const float*)d_in[8];
  const float* bih_r = (const float*)d_in[9];
  const float* bhh_r = (const float*)d_in[10];
  const float* Wc    = (const float*)d_in[11];
  const float* bc    = (const float*)d_in[12];
  const float* Wih_w = (const float*)d_in[13];
  const float* Whh_w = (const float*)d_in[14];
  const float* bih_w = (const float*)d_in[15];
  const float* bhh_w = (const float*)d_in[16];
  float* out = (float*)d_out;

  char* ws = (char*)d_ws;
  u32* WAp  = (u32*)(ws);                        // 262144 u32 = 1 MB
  u32* WEp  = (u32*)(ws + 1048576);              // 1 MB
  u32* Wcp  = (u32*)(ws + 2097152);              // 256 KB
  float* bA = (float*)(ws + 2359296);            // 4 KB
  float* bE = (float*)(ws + 2363392);            // 4 KB
  float* bcf= (float*)(ws + 2367488);            // 1 KB
  unsigned char* mbuf = (unsigned char*)(ws + 2368512);  // 128 KB
  float* hrbuf = (float*)(ws + 2499584);         // 32*128*256 f32 = 4 MB
  u32* prog = (u32*)(ws + 6693888);              // 128 u32

  k_prep<<<dim3(707), dim3(1024), 0, stream>>>(
      Wih_r, Whh_r, bih_r, bhh_r, Wc, bc, Wih_w, Whh_w, bih_w, bhh_w,
      maskraw, WAp, WEp, Wcp, bA, bE, bcf, mbuf, prog);
  k_main<<<dim3(256), dim3(1024), 0, stream>>>(
      emb, hr0, cr0, hw0, cw0, M0, WAp, WEp, Wcp, bA, bE, bcf, mbuf,
      hrbuf, prog, out);
}

// Round 2
// 809.368 us; speedup vs baseline: 1.3571x; 1.0637x over previous
//
#include <hip/hip_runtime.h>
#include <math.h>

typedef unsigned short u16;
typedef unsigned int u32;
typedef __attribute__((ext_vector_type(2))) _Float16 h2;

#define kT 32
#define OUT_STATES 1048576   // T*B*D
#define OUT_M      1179648   // + 4*B*D

union H2U { u32 u; h2 h; };

__device__ __forceinline__ float dot2u(u32 w, u32 x, float acc){
  H2U a; a.u = w; H2U b; b.u = x;
#if __has_builtin(__builtin_amdgcn_fdot2)
  return __builtin_amdgcn_fdot2(a.h, b.h, acc, false);
#else
  acc += (float)a.h.x * (float)b.h.x;
  acc += (float)a.h.y * (float)b.h.y;
  return acc;
#endif
}

__device__ __forceinline__ u32 packf16(float x, float y){
  H2U v; v.h.x = (_Float16)x; v.h.y = (_Float16)y; return v.u;
}

// ---- prep: weights -> packed f16 [k/2][col] layout, biases summed, mask ------
__global__ __launch_bounds__(1024) void k_prep(
        const float* __restrict__ Wih_r, const float* __restrict__ Whh_r,
        const float* __restrict__ bih_r, const float* __restrict__ bhh_r,
        const float* __restrict__ Wc,    const float* __restrict__ bc,
        const float* __restrict__ Wih_w, const float* __restrict__ Whh_w,
        const float* __restrict__ bih_w, const float* __restrict__ bhh_w,
        const unsigned char* __restrict__ maskraw,
        u32* WAp, u32* WEp, u32* Wcp, float* bA, float* bE, float* bcf,
        unsigned char* mbuf, u32* prog){
  int idx = blockIdx.x * 1024 + threadIdx.x;
  if (idx < 262144){
    int kp = idx >> 10, col = idx & 1023;
    int k0 = 2 * kp;
    float v0 = (k0 < 256) ? Wih_r[col * 256 + k0] : Whh_r[col * 256 + k0 - 256];
    float v1 = (k0 + 1 < 256) ? Wih_r[col * 256 + k0 + 1]
                              : Whh_r[col * 256 + k0 + 1 - 256];
    WAp[idx] = packf16(v0, v1);
  } else if (idx < 524288){
    int i = idx - 262144;
    int kp = i >> 10, col = i & 1023;
    int k0 = 2 * kp;
    float v0 = (k0 < 256) ? Wih_w[col * 256 + k0] : Whh_w[col * 256 + k0 - 256];
    float v1 = (k0 + 1 < 256) ? Wih_w[col * 256 + k0 + 1]
                              : Whh_w[col * 256 + k0 + 1 - 256];
    WEp[i] = packf16(v0, v1);
  } else if (idx < 589824){
    int i = idx - 524288;
    int kp = i >> 8, col = i & 255;
    int k0 = 2 * kp;
    Wcp[i] = packf16(Wc[col * 512 + k0], Wc[col * 512 + k0 + 1]);
  } else if (idx < 590848){
    int i = idx - 589824;
    bA[i] = bih_r[i] + bhh_r[i];
  } else if (idx < 591872){
    int i = idx - 590848;
    bE[i] = bih_w[i] + bhh_w[i];
  } else if (idx < 592128){
    int i = idx - 591872;
    bcf[i] = bc[i];
  } else if (idx < 723200){
    int l = idx - 592128;
    // Detect mask storage: int32 / u8(bool) / bf16 / fp32 from first 512 bytes.
    bool sawBig = false, sawOdd = false, saw3F1 = false;
    for (int i = 0; i < 512; i++){
      unsigned char c = maskraw[i];
      if (c > 1u) sawBig = true;
      if ((i & 3) != 0 && c != 0) sawOdd = true;
      if ((i & 3) == 1 && c == 0x3F) saw3F1 = true;
    }
    int mode = (!sawBig) ? (sawOdd ? 1 : 0) : (saw3F1 ? 2 : 3);
    unsigned char mv;
    if      (mode == 0) mv = (((const int*)maskraw)[l] != 0);
    else if (mode == 1) mv = (maskraw[l] != 0);
    else if (mode == 2) mv = ((maskraw[2*l] | maskraw[2*l+1]) != 0);
    else                mv = (((const unsigned int*)maskraw)[l] != 0);
    mbuf[l] = mv;
  } else if (idx < 723584){
    prog[idx - 723200] = 0;     // reset progR/progW/progGW each launch
  }
}

// ---- k_pre: gxp[t][b][cp] = packed f16 pairs of (emb[t,b,:] @ Wih_r^T) ------
// grid (32,8): block = (t, 128-col tile). Uses WAp kp<128 (= Wih_r half).
__global__ __launch_bounds__(1024) void k_pre(
        const float* __restrict__ emb, const u32* __restrict__ WAp,
        u32* __restrict__ gxp){
  __shared__ u32 wt[16384];          // [kp 128][c 128]
  __shared__ u32 xt[128 * 129];      // [b 128][kp 128], padded stride
  int t = blockIdx.x, c0 = blockIdx.y * 128, tid = threadIdx.x;
  for (int i = 0; i < 16; i++){
    int idx = i * 1024 + tid;
    wt[idx] = WAp[(idx >> 7) * 1024 + c0 + (idx & 127)];
    int b = idx >> 7, kp = idx & 127;
    float2 e2 = *(const float2*)(emb + (size_t)t * 32768 + b * 256 + 2 * kp);
    xt[b * 129 + kp] = packf16(e2.x, e2.y);
  }
  __syncthreads();
  int b = tid & 127, cg = tid >> 7;    // wave-uniform cg -> broadcast wt reads
  float acc[16];
  #pragma unroll
  for (int j = 0; j < 16; j++) acc[j] = 0.f;
  const u32* xrow = xt + b * 129;
  for (int kp = 0; kp < 128; kp++){
    u32 xv = xrow[kp];
    const uint4* wr = (const uint4*)(wt + kp * 128 + cg * 16);
    #pragma unroll
    for (int j4 = 0; j4 < 4; j4++){
      uint4 wv = wr[j4];
      acc[4*j4+0] = dot2u(wv.x, xv, acc[4*j4+0]);
      acc[4*j4+1] = dot2u(wv.y, xv, acc[4*j4+1]);
      acc[4*j4+2] = dot2u(wv.z, xv, acc[4*j4+2]);
      acc[4*j4+3] = dot2u(wv.w, xv, acc[4*j4+3]);
    }
  }
  u32* gp = gxp + ((size_t)t * 128 + b) * 512 + (c0 >> 1) + cg * 8;
  #pragma unroll
  for (int i = 0; i < 8; i++) gp[i] = packf16(acc[2*i], acc[2*i+1]);
}

// gemv K=256 (128 half2 rows), 1024 cols. thread = (cg: 4 cols, ks: 4 slices)
__device__ __forceinline__ void gemv256(const u32* __restrict__ W,
        const u32* xh, float* psum, int tid){
  int cg = tid & 255, ks = tid >> 8;
  const uint4* wp = (const uint4*)W + (size_t)ks * 32 * 256 + cg;
  const u32* xk = xh + ks * 32;
  float a0 = 0.f, a1 = 0.f, a2 = 0.f, a3 = 0.f;
  #pragma unroll 8
  for (int i = 0; i < 32; i++){
    uint4 wv = wp[(size_t)i * 256];
    u32 xp = xk[i];
    a0 = dot2u(wv.x, xp, a0);  a1 = dot2u(wv.y, xp, a1);
    a2 = dot2u(wv.z, xp, a2);  a3 = dot2u(wv.w, xp, a3);
  }
  float4 r; r.x = a0; r.y = a1; r.z = a2; r.w = a3;
  *(float4*)&psum[ks * 1024 + cg * 4] = r;
}

// ---- main: 256 blocks. R blocks [0,128): hr chain + Whh_w@hw_{t-1} offload.
//            W blocks [128,256): attention + comp + write-LSTM finish.
// Handoffs via agent-scope relaxed atomics; flags after __syncthreads() drain.
// Dependency cycle: W_{t-1} -> R_t(ph2) -> W_t(final) and R's own ph1 chain.
__global__ __launch_bounds__(1024, 4) void k_main(
        const float* __restrict__ emb, const float* __restrict__ hr0,
        const float* __restrict__ cr0, const float* __restrict__ hw0,
        const float* __restrict__ cw0, const float* __restrict__ M0,
        const u32* __restrict__ WAp, const u32* __restrict__ WEp,
        const u32* __restrict__ Wcp, const float* __restrict__ bA,
        const float* __restrict__ bE, const float* __restrict__ bcf,
        const unsigned char* __restrict__ mbuf,
        const u32* __restrict__ gxp,
        float* __restrict__ hrbuf, float* __restrict__ hwbuf,
        float* __restrict__ gwbuf, u32* __restrict__ prog,
        float* __restrict__ out){
  __shared__ u32 xh[256];
  __shared__ __attribute__((aligned(16))) float hr_s[256];
  __shared__ __attribute__((aligned(16))) float hw_f[256];
  __shared__ float m_f[256], comp_f[256], c_l[256];
  __shared__ __attribute__((aligned(16))) float psum[4160];
  __shared__ float z_lds[1024];
  __shared__ float redA[16], redB[16], redC[16], redD[16], wred[16], sred[16];
  __shared__ unsigned char mk[1024];

  int bid = blockIdx.x;
  int role = bid >> 7, b = bid & 127;
  int tid = threadIdx.x;
  int w = tid >> 6, lane = tid & 63;
  u32* progR  = prog;
  u32* progW  = prog + 128;
  u32* progGW = prog + 256;

  if (role == 0){
    // ================= R: read-LSTM + write-gemv offload =================
    const u32* WRh = WAp + 128 * 1024;   // Whh_r half (kp 128..255)
    const u32* WEh = WEp + 128 * 1024;   // Whh_w half (kp 128..255)
    if (tid < 256){
      hr_s[tid] = hr0[b * 256 + tid];
      c_l[tid]  = cr0[b * 256 + tid];
    }
    __syncthreads();

    for (int t = 0; t < kT; t++){
      // ---- ph1: hr_t = LSTM(gx_t + Whh_r @ hr_{t-1}) ----
      if (tid < 128) xh[tid] = packf16(hr_s[2 * tid], hr_s[2 * tid + 1]);
      __syncthreads();
      u32 gx0 = 0, gx1 = 0, gx2 = 0, gx3 = 0;
      if (tid < 256){
        const u32* gx = gxp + ((size_t)t * 128 + b) * 512;
        gx0 = gx[tid >> 1];          gx1 = gx[128 + (tid >> 1)];
        gx2 = gx[256 + (tid >> 1)];  gx3 = gx[384 + (tid >> 1)];
      }
      gemv256(WRh, xh, psum, tid);
      __syncthreads();
      if (tid < 256){
        H2U p0, p1, p2, p3;
        p0.u = gx0; p1.u = gx1; p2.u = gx2; p3.u = gx3;
        int hi = tid & 1;
        float gi = (hi ? (float)p0.h.y : (float)p0.h.x) + bA[tid];
        float gf = (hi ? (float)p1.h.y : (float)p1.h.x) + bA[256 + tid];
        float gg = (hi ? (float)p2.h.y : (float)p2.h.x) + bA[512 + tid];
        float go = (hi ? (float)p3.h.y : (float)p3.h.x) + bA[768 + tid];
        #pragma unroll
        for (int ks = 0; ks < 4; ks++){
          gi += psum[ks * 1024 + tid];
          gf += psum[ks * 1024 + 256 + tid];
          gg += psum[ks * 1024 + 512 + tid];
          go += psum[ks * 1024 + 768 + tid];
        }
        float i_ = 1.f / (1.f + expf(-gi));
        float f_ = 1.f / (1.f + expf(-gf));
        float g_ = tanhf(gg);
        float o_ = 1.f / (1.f + expf(-go));
        float c2 = f_ * c_l[tid] + i_ * g_;
        c_l[tid] = c2;
        float h = o_ * tanhf(c2);
        hr_s[tid] = h;
        __hip_atomic_store(hrbuf + (size_t)t * 32768 + b * 256 + tid, h,
                           __ATOMIC_RELAXED, __HIP_MEMORY_SCOPE_AGENT);
      }
      __syncthreads();   // vmcnt(0) drain before flag
      if (tid == 0)
        __hip_atomic_store(progR + b, (u32)(t + 1),
                           __ATOMIC_RELAXED, __HIP_MEMORY_SCOPE_AGENT);

      // ---- ph2: gw = Whh_w @ hw_{t-1}  (off W's critical path) ----
      if (t == 0){
        if (tid < 128){
          float2 h0 = *(const float2*)(hw0 + b * 256 + 2 * tid);
          xh[tid] = packf16(h0.x, h0.y);
        }
      } else {
        if (tid == 0){
          while (__hip_atomic_load(progW + b, __ATOMIC_RELAXED,
                                   __HIP_MEMORY_SCOPE_AGENT) < (u32)t)
            __builtin_amdgcn_s_sleep(2);
        }
        __syncthreads();
        if (tid < 128){
          float x0 = __hip_atomic_load(hwbuf + b * 256 + 2 * tid,
                                       __ATOMIC_RELAXED, __HIP_MEMORY_SCOPE_AGENT);
          float x1 = __hip_atomic_load(hwbuf + b * 256 + 2 * tid + 1,
                                       __ATOMIC_RELAXED, __HIP_MEMORY_SCOPE_AGENT);
          xh[tid] = packf16(x0, x1);
        }
      }
      __syncthreads();
      gemv256(WEh, xh, psum, tid);
      __syncthreads();
      {
        float g = psum[tid] + psum[1024 + tid] + psum[2048 + tid]
                + psum[3072 + tid];
        __hip_atomic_store(gwbuf + b * 1024 + tid, g,
                           __ATOMIC_RELAXED, __HIP_MEMORY_SCOPE_AGENT);
      }
      __syncthreads();   // drain before flag
      if (tid == 0)
        __hip_atomic_store(progGW + b, (u32)(t + 1),
                           __ATOMIC_RELAXED, __HIP_MEMORY_SCOPE_AGENT);
    }
    if (tid < 256){
      out[OUT_STATES          + b * 256 + tid] = hr_s[tid];
      out[OUT_STATES +  32768 + b * 256 + tid] = c_l[tid];
    }
    return;
  }

  // ================= W: attention + comp + write-LSTM finish ================
  if (tid < 256){
    hw_f[tid] = hw0[b * 256 + tid];
    c_l[tid]  = cw0[b * 256 + tid];
  }
  unsigned char mreg = mbuf[b * 1024 + tid];
  mk[tid] = mreg;
  float zreg = 0.f;
  __syncthreads();

  for (int t = 0; t < kT; t++){
    // ---------- wait for hr_t ----------
    if (tid == 0){
      while (__hip_atomic_load(progR + b, __ATOMIC_RELAXED,
                               __HIP_MEMORY_SCOPE_AGENT) < (u32)(t + 1))
        __builtin_amdgcn_s_sleep(2);
    }
    __syncthreads();
    if (tid < 256)
      hr_s[tid] = __hip_atomic_load(hrbuf + (size_t)t * 32768 + b * 256 + tid,
                                    __ATOMIC_RELAXED, __HIP_MEMORY_SCOPE_AGENT);
    __syncthreads();

    // ---------- Phase C: attention ----------
    if (t == 0){
      float4 hrv = *(const float4*)&hr_s[lane * 4];
      float run_max = -INFINITY, S = 0.f;
      float m0 = 0.f, m1 = 0.f, m2 = 0.f, m3 = 0.f;
      for (int l = w * 64; l < w * 64 + 64; ++l){
        float4 Mv = *(const float4*)(M0 + ((size_t)b * 1024 + l) * 256 + lane * 4);
        float part = Mv.x * hrv.x + Mv.y * hrv.y + Mv.z * hrv.z + Mv.w * hrv.w;
        #pragma unroll
        for (int mm = 32; mm >= 1; mm >>= 1) part += __shfl_xor(part, mm, 64);
        float s = mk[l] ? -INFINITY : part;
        if (lane == 0) z_lds[l] = s;
        float nm = fmaxf(run_max, s);
        if (nm > -INFINITY){
          float sc = expf(run_max - nm);
          float p  = expf(s - nm);
          S = S * sc + p;
          m0 = m0 * sc + p * Mv.x;  m1 = m1 * sc + p * Mv.y;
          m2 = m2 * sc + p * Mv.z;  m3 = m3 * sc + p * Mv.w;
          run_max = nm;
        }
      }
      if (lane == 0){ wred[w] = run_max; sred[w] = S; }
      psum[w * 260 + lane * 4 + 0] = m0;
      psum[w * 260 + lane * 4 + 1] = m1;
      psum[w * 260 + lane * 4 + 2] = m2;
      psum[w * 260 + lane * 4 + 3] = m3;
      __syncthreads();
      float gmax = -INFINITY;
      #pragma unroll
      for (int w2 = 0; w2 < 16; w2++) gmax = fmaxf(gmax, wred[w2]);
      float Sg = 0.f;
      #pragma unroll
      for (int w2 = 0; w2 < 16; w2++) Sg += sred[w2] * expf(wred[w2] - gmax);
      zreg = expf(z_lds[tid] - gmax) / Sg;
      if (tid < 256){
        float mv = 0.f;
        #pragma unroll
        for (int w2 = 0; w2 < 16; w2++)
          mv += psum[w2 * 260 + tid] * expf(wred[w2] - gmax);
        m_f[tid] = mv / Sg;
      }
    } else {
      // factored memory: M = (1-zp) + hw_prev (x) zp
      float hrv = (tid < 256) ? hr_s[tid] : 0.f;
      float hwv = (tid < 256) ? hw_f[tid] : 0.f;
      float v1 = hrv, v2 = hrv * hwv;
      #pragma unroll
      for (int mm = 32; mm >= 1; mm >>= 1){
        v1 += __shfl_xor(v1, mm, 64);  v2 += __shfl_xor(v2, mm, 64);
      }
      if (lane == 0){ redA[w] = v1; redB[w] = v2; }
      __syncthreads();
      float S1 = 0.f, S2 = 0.f;
      #pragma unroll
      for (int i = 0; i < 16; i++){ S1 += redA[i]; S2 += redB[i]; }
      float zold = zreg;
      float s = mreg ? -INFINITY : (1.f - zold) * S1 + zold * S2;
      float mx = s;
      #pragma unroll
      for (int mm = 32; mm >= 1; mm >>= 1) mx = fmaxf(mx, __shfl_xor(mx, mm, 64));
      if (lane == 0) redC[w] = mx;
      __syncthreads();
      float gmax = -INFINITY;
      #pragma unroll
      for (int i = 0; i < 16; i++) gmax = fmaxf(gmax, redC[i]);
      float p = expf(s - gmax);            // -inf -> 0
      float ps = p;
      #pragma unroll
      for (int mm = 32; mm >= 1; mm >>= 1) ps += __shfl_xor(ps, mm, 64);
      if (lane == 0) redD[w] = ps;
      __syncthreads();
      float Ssum = 0.f;
      #pragma unroll
      for (int i = 0; i < 16; i++) Ssum += redD[i];
      float znew = p / Ssum;
      float a1 = znew * (1.f - zold), a2 = znew * zold;
      #pragma unroll
      for (int mm = 32; mm >= 1; mm >>= 1){
        a1 += __shfl_xor(a1, mm, 64);  a2 += __shfl_xor(a2, mm, 64);
      }
      if (lane == 0){ redA[w] = a1; redB[w] = a2; }
      __syncthreads();
      float Ab = 0.f, Cb = 0.f;
      #pragma unroll
      for (int i = 0; i < 16; i++){ Ab += redA[i]; Cb += redB[i]; }
      zreg = znew;
      if (tid < 256) m_f[tid] = Ab + hw_f[tid] * Cb;
    }
    __syncthreads();

    // ---------- pre-softmax comp: e = Wc @ [hr;m] + bc ----------
    if (tid < 128) xh[tid] = packf16(hr_s[2 * tid], hr_s[2 * tid + 1]);
    else if (tid < 256){
      int j = tid - 128;
      xh[tid] = packf16(m_f[2 * j], m_f[2 * j + 1]);
    }
    __syncthreads();
    {
      int cg = tid & 63, ks = tid >> 6;
      const uint4* wp = (const uint4*)Wcp + ks * 16 * 64 + cg;
      const u32* xk = xh + ks * 16;
      float a0 = 0.f, a1 = 0.f, a2 = 0.f, a3 = 0.f;
      #pragma unroll
      for (int i = 0; i < 16; i++){
        uint4 wv = wp[i * 64];
        u32 xp = xk[i];
        a0 = dot2u(wv.x, xp, a0);  a1 = dot2u(wv.y, xp, a1);
        a2 = dot2u(wv.z, xp, a2);  a3 = dot2u(wv.w, xp, a3);
      }
      float4 r; r.x = a0; r.y = a1; r.z = a2; r.w = a3;
      *(float4*)&psum[ks * 256 + cg * 4] = r;
    }
    __syncthreads();
    float esum;
    {
      float e = -INFINITY;
      if (tid < 256){
        e = bcf[tid];
        #pragma unroll
        for (int s2 = 0; s2 < 16; s2++) e += psum[s2 * 256 + tid];
      }
      float mx = e;
      #pragma unroll
      for (int mm = 32; mm >= 1; mm >>= 1) mx = fmaxf(mx, __shfl_xor(mx, mm, 64));
      if (lane == 0) redC[w] = mx;
      __syncthreads();
      float emax = -INFINITY;
      #pragma unroll
      for (int i = 0; i < 16; i++) emax = fmaxf(emax, redC[i]);
      float pe = (tid < 256) ? expf(e - emax) : 0.f;
      float ps = pe;
      #pragma unroll
      for (int mm = 32; mm >= 1; mm >>= 1) ps += __shfl_xor(ps, mm, 64);
      if (lane == 0) redD[w] = ps;
      if (tid < 256) comp_f[tid] = pe;     // unnormalized; divide folded later
      __syncthreads();
      esum = 0.f;
      #pragma unroll
      for (int i = 0; i < 16; i++) esum += redD[i];
    }

    // ---------- Phase E: Wih_w @ pe (K=256), then combine with R's gw ----
    if (tid < 128) xh[tid] = packf16(comp_f[2 * tid], comp_f[2 * tid + 1]);
    __syncthreads();
    gemv256(WEp, xh, psum, tid);     // Wih_w half (kp 0..127)
    __syncthreads();
    if (tid == 0){
      while (__hip_atomic_load(progGW + b, __ATOMIC_RELAXED,
                               __HIP_MEMORY_SCOPE_AGENT) < (u32)(t + 1))
        __builtin_amdgcn_s_sleep(2);
    }
    __syncthreads();
    if (tid < 256){
      float rinv = 1.f / esum;
      float gi = bE[tid]
               + __hip_atomic_load(gwbuf + b * 1024 + tid,
                                   __ATOMIC_RELAXED, __HIP_MEMORY_SCOPE_AGENT);
      float gf = bE[256 + tid]
               + __hip_atomic_load(gwbuf + b * 1024 + 256 + tid,
                                   __ATOMIC_RELAXED, __HIP_MEMORY_SCOPE_AGENT);
      float gg = bE[512 + tid]
               + __hip_atomic_load(gwbuf + b * 1024 + 512 + tid,
                                   __ATOMIC_RELAXED, __HIP_MEMORY_SCOPE_AGENT);
      float go = bE[768 + tid]
               + __hip_atomic_load(gwbuf + b * 1024 + 768 + tid,
                                   __ATOMIC_RELAXED, __HIP_MEMORY_SCOPE_AGENT);
      float si = 0.f, sf = 0.f, sg = 0.f, so = 0.f;
      #pragma unroll
      for (int ks = 0; ks < 4; ks++){
        si += psum[ks * 1024 + tid];
        sf += psum[ks * 1024 + 256 + tid];
        sg += psum[ks * 1024 + 512 + tid];
        so += psum[ks * 1024 + 768 + tid];
      }
      gi += si * rinv;  gf += sf * rinv;  gg += sg * rinv;  go += so * rinv;
      float i_ = 1.f / (1.f + expf(-gi));
      float f_ = 1.f / (1.f + expf(-gf));
      float g_ = tanhf(gg);
      float o_ = 1.f / (1.f + expf(-go));
      float c2 = f_ * c_l[tid] + i_ * g_;
      c_l[tid] = c2;
      float h2v = o_ * tanhf(c2);
      hw_f[tid] = h2v;
      out[(size_t)t * 32768 + b * 256 + tid] = h2v;
      __hip_atomic_store(hwbuf + b * 256 + tid, h2v,
                         __ATOMIC_RELAXED, __HIP_MEMORY_SCOPE_AGENT);
    }
    __syncthreads();   // drain before flag
    if (tid == 0)
      __hip_atomic_store(progW + b, (u32)(t + 1),
                         __ATOMIC_RELAXED, __HIP_MEMORY_SCOPE_AGENT);
  }

  // ---------- epilogue: states + M = (1-z) + hw (x) z ----------
  if (tid < 256){
    out[OUT_STATES +  65536 + b * 256 + tid] = hw_f[tid];
    out[OUT_STATES +  98304 + b * 256 + tid] = c_l[tid];
  }
  z_lds[tid] = zreg;
  __syncthreads();
  float* Mout = out + OUT_M + (size_t)b * 262144;
  for (int g = tid; g < 65536; g += 1024){
    int l = g >> 6, d0 = (g & 63) << 2;
    float z = z_lds[l], omz = 1.f - z;
    float4 h4 = *(const float4*)&hw_f[d0];
    float4 v;
    v.x = omz + h4.x * z;  v.y = omz + h4.y * z;
    v.z = omz + h4.z * z;  v.w = omz + h4.w * z;
    *(float4*)(Mout + (size_t)l * 256 + d0) = v;
  }
}

extern "C" void kernel_launch(void* const* d_in, const int* in_sizes, int n_in,
                              void* d_out, int out_size, void* d_ws, size_t ws_size,
                              hipStream_t stream){
  const float* emb   = (const float*)d_in[0];
  const float* hr0   = (const float*)d_in[1];
  const float* cr0   = (const float*)d_in[2];
  const float* hw0   = (const float*)d_in[3];
  const float* cw0   = (const float*)d_in[4];
  const float* M0    = (const float*)d_in[5];
  const unsigned char* maskraw = (const unsigned char*)d_in[6];
  const float* Wih_r = (const float*)d_in[7];
  const float* Whh_r = (const float*)d_in[8];
  const float* bih_r = (const float*)d_in[9];
  const float* bhh_r = (const float*)d_in[10];
  const float* Wc    = (const float*)d_in[11];
  const float* bc    = (const float*)d_in[12];
  const float* Wih_w = (const float*)d_in[13];
  const float* Whh_w = (const float*)d_in[14];
  const float* bih_w = (const float*)d_in[15];
  const float* bhh_w = (const float*)d_in[16];
  float* out = (float*)d_out;

  char* ws = (char*)d_ws;
  u32* WAp  = (u32*)(ws);                        // 1 MB
  u32* WEp  = (u32*)(ws + 1048576);              // 1 MB
  u32* Wcp  = (u32*)(ws + 2097152);              // 256 KB
  float* bA = (float*)(ws + 2359296);            // 4 KB
  float* bE = (float*)(ws + 2363392);            // 4 KB
  float* bcf= (float*)(ws + 2367488);            // 1 KB
  unsigned char* mbuf = (unsigned char*)(ws + 2368512);  // 128 KB
  float* hrbuf = (float*)(ws + 2499584);         // 4 MB
  u32* prog    = (u32*)(ws + 6693888);           // 384 u32 (progR/W/GW)
  float* gwbuf = (float*)(ws + 6695424);         // 512 KB
  float* hwbuf = (float*)(ws + 7219712);         // 128 KB
  u32* gxp     = (u32*)(ws + 7350784);           // 8 MB

  k_prep<<<dim3(707), dim3(1024), 0, stream>>>(
      Wih_r, Whh_r, bih_r, bhh_r, Wc, bc, Wih_w, Whh_w, bih_w, bhh_w,
      maskraw, WAp, WEp, Wcp, bA, bE, bcf, mbuf, prog);
  k_pre<<<dim3(32, 8), dim3(1024), 0, stream>>>(emb, WAp, gxp);
  k_main<<<dim3(256), dim3(1024), 0, stream>>>(
      emb, hr0, cr0, hw0, cw0, M0, WAp, WEp, Wcp, bA, bE, bcf, mbuf,
      gxp, hrbuf, hwbuf, gwbuf, prog, out);
}